// Round 2
// baseline (385.271 us; speedup 1.0000x reference)
//
#include <hip/hip_runtime.h>
#include <cstddef>

// ---------------------------------------------------------------------------
// Fused equivariant decoder, MI355X (gfx950) — round 6.
// B_ROWS=16 (all MFMA tiles full). 3 barriers total (phase 1 only).
// R5: phase-2 H handoffs (L1->L2, L2->L3) entirely in registers via
//     ds_bpermute; per-wave LDS scratch deleted (LDS 48.4 KB -> 29.9 KB).
// R6 (this round): each wave issues its FIRST phase-2 B-gather before
//     phase 1, hiding the ~600-900 cy HBM gather latency under the three
//     barriered scalar layers. No other changes (R5 still unmeasured —
//     keeping attribution clean).
// Weights pre-packed as A-operand fragments (W^T/sqrt(K)) in d_ws.
// ---------------------------------------------------------------------------

typedef _Float16 half8 __attribute__((ext_vector_type(8)));
typedef _Float16 half4 __attribute__((ext_vector_type(4)));
typedef float    f32x4 __attribute__((ext_vector_type(4)));
typedef float    fvec4 __attribute__((ext_vector_type(4)));
typedef unsigned int u32x4 __attribute__((ext_vector_type(4)));

#define B_ROWS   16
#define IN_DIM   3840
#define OUT_COLS 49
#define GP  264           // gate row pitch (256 used)
#define HSP 72            // scalar-hidden row pitch (64 used)

// LDS map (elements of _Float16); bases all 16B-aligned.
#define OFF_G1  0         // 16*264 = 4224
#define OFF_G2  4224
#define OFF_G3  8448
#define OFF_HS1 12672     // 16*72 = 1152
#define OFF_HS2 13824
#define SMEM_ELTS 14976   // *2B = 29952 B

#define P2BASE 106496
#define P3BASE 139264

// ---------------------------------------------------------------------------
// Weight prep (same packed layout as R2-R5; consumed as A-fragments).
// Frag f=(mt*KF+kf)*64+lane holds W[i][o]*scale, i=kf*32+(lane>>4)*8+j,
// o=mt*16+(lane&15).
// ---------------------------------------------------------------------------
__global__ __launch_bounds__(256) void prep_weights(
    const float* __restrict__ w1, const float* __restrict__ w2,
    const float* __restrict__ w3, _Float16* __restrict__ packed)
{
  static const int K_[24]    = {256,256,128,128,64,64,64,64,  64,64,64,64,32,32,32,32,
                                64,64,64,64,32,32,32,32};
  static const int N_[24]    = {64,256,64,64,32,32,32,32,  64,256,64,64,32,32,32,32,
                                64,256,64,64,32,32,32,32};
  static const int woff_[24] = {0,16384,81920,90112,98304,100352,102400,104448,
                                0,4096,20480,24576,28672,29696,30720,31744,
                                0,4096,20480,24576,28672,29696,30720,31744};
  static const int poff_[24] = {0,16384,81920,90112,98304,100352,102400,104448,
                                106496,110592,126976,131072,135168,136192,137216,138240,
                                139264,143360,159744,163840,167936,168960,169984,171008};
  const int g = blockIdx.x * 256 + threadIdx.x;   // 0 .. 21503
  int bi = 0;
#pragma unroll
  for (int i = 1; i < 24; ++i) if (g * 8 >= poff_[i]) bi = i;
  const float* w = (bi < 8) ? w1 : ((bi < 16) ? w2 : w3);
  const int rel8 = g - poff_[bi] / 8;
  const int lane = rel8 & 63;
  const int fi   = rel8 >> 6;
  const int K = K_[bi], N = N_[bi];
  const int KF = K >> 5;
  const int kf = fi % KF;
  const int mt = fi / KF;
  const int k0 = kf * 32 + (lane >> 4) * 8;
  const int o  = mt * 16 + (lane & 15);
  const float scale = 1.0f / sqrtf((float)K);
  half8 vv;
#pragma unroll
  for (int j = 0; j < 8; ++j)
    vv[j] = (_Float16)(w[woff_[bi] + (size_t)(k0 + j) * N + o] * scale);
  *(half8*)(packed + (size_t)g * 8) = vv;
}

// ---------------------------------------------------------------------------
// Per-chain compile-time parameters.
// ---------------------------------------------------------------------------
template<int L> struct CP {
  static constexpr int TWOL1 = 2 * L + 1;
  static constexpr int K1  = (L <= 2) ? 128 : 64;
  static constexpr int N1  = (L <= 2) ? 64  : 32;
  static constexpr int KF1 = K1 / 32;
  static constexpr int KF2 = N1 / 32;          // == MT/2
  static constexpr int MT  = N1 / 16;
  static constexpr int INOFF = (L==1)?256:(L==2)?640:(L==3)?1280:(L==4)?1728:(L==5)?2304:3008;
  static constexpr int P1    = (L==1)?81920:(L==2)?90112:(L==3)?98304:(L==4)?100352:(L==5)?102400:104448;
  static constexpr int P2R   = (L==1)?20480:(L==2)?24576:(L==3)?28672:(L==4)?29696:(L==5)?30720:31744;
  static constexpr int GO    = (L==1)?0:(L==2)?64:(L==3)?128:(L==4)?160:(L==5)?192:224;
  static constexpr int W4O   = (L==1)?64:(L==2)?128:(L==3)?192:(L==4)?224:(L==5)?256:288;
  static constexpr float SCALE = (N1 == 64) ? 0.125f : 0.17677669529663687f;
};

// Pack two floats into one u32 of 2 halves (lo first).
__device__ __forceinline__ unsigned pack2(float x, float y)
{
  const unsigned short lo = __builtin_bit_cast(unsigned short, (_Float16)x);
  const unsigned short hi = __builtin_bit_cast(unsigned short, (_Float16)y);
  return ((unsigned)hi << 16) | (unsigned)lo;
}

// ---------------------------------------------------------------------------
// In-register H handoff. After an MFMA layer + gating, lane (col,quad) holds
// packed halves p[mt][0..1] = H[col][mt*16+quad*4 + {0,1 | 2,3}]. The next
// layer's B-fragment needs bv[h][j] = H[col][h*32 + quad*8 + j], j=0..7.
// Derivation: o = h*32+quad*8+j  ->  src mt = 2h+(quad>>1),
//   src quad = 2*(quad&1) (+1 for j>=4), src reg r = j&3.
// So: srcA lane = col + 32*(quad&1), srcB = srcA+16; pull p[2h] and p[2h+1]
// from both and select by (quad>>1). 8 ds_bpermute + 4 cndmask per h.
// ---------------------------------------------------------------------------
template<int MT>
__device__ __forceinline__ void exchange(const unsigned (&p)[MT][2],
                                         half8 (&bv)[MT / 2])
{
  const int lane  = threadIdx.x & 63;
  const int addrA = (((lane & 15) + ((lane & 16) << 1)) << 2); // (col + 32*(q&1))*4
  const int addrB = addrA + 64;
  const bool useHi = (lane & 32) != 0;                          // quad >= 2
#pragma unroll
  for (int h = 0; h < MT / 2; ++h) {
    const int a0 = __builtin_amdgcn_ds_bpermute(addrA, (int)p[2 * h][0]);
    const int a1 = __builtin_amdgcn_ds_bpermute(addrA, (int)p[2 * h][1]);
    const int a2 = __builtin_amdgcn_ds_bpermute(addrA, (int)p[2 * h + 1][0]);
    const int a3 = __builtin_amdgcn_ds_bpermute(addrA, (int)p[2 * h + 1][1]);
    const int b0 = __builtin_amdgcn_ds_bpermute(addrB, (int)p[2 * h][0]);
    const int b1 = __builtin_amdgcn_ds_bpermute(addrB, (int)p[2 * h][1]);
    const int b2 = __builtin_amdgcn_ds_bpermute(addrB, (int)p[2 * h + 1][0]);
    const int b3 = __builtin_amdgcn_ds_bpermute(addrB, (int)p[2 * h + 1][1]);
    u32x4 w;
    w[0] = (unsigned)(useHi ? a2 : a0);   // j0,j1
    w[1] = (unsigned)(useHi ? a3 : a1);   // j2,j3
    w[2] = (unsigned)(useHi ? b2 : b0);   // j4,j5
    w[3] = (unsigned)(useHi ? b3 : b1);   // j6,j7
    bv[h] = __builtin_bit_cast(half8, w);
  }
}

// Direct global B-frag loads for one unit: lane (col,quad) needs
// X[c][kf*32+quad*8+j] = vraw[(b0+b)*IN_DIM + INOFF + i*TWOL1 + m].
template<int L>
__device__ __forceinline__ void unit_load(const float* __restrict__ vraw,
                                          int b0, int ct, float (&rg)[CP<L>::KF1 * 8])
{
  using P = CP<L>;
  const int lane = threadIdx.x & 63;
  const int col  = lane & 15;
  const int quad = lane >> 4;
  const int c = ct * 16 + col;
  const int b = c / P::TWOL1;
  const int m = c - b * P::TWOL1;
  const float* base = vraw + (size_t)(b0 + b) * IN_DIM + P::INOFF + m
                    + (size_t)(quad * 8) * P::TWOL1;
#pragma unroll
  for (int kf = 0; kf < P::KF1; ++kf)
#pragma unroll
    for (int j = 0; j < 8; ++j)
      rg[kf * 8 + j] = base[(size_t)(kf * 32 + j) * P::TWOL1];
}

// One unit: L1(gate G1) -> L2(G2) -> L3(G3)+w4 dot. H handoffs fully
// in-register via exchange<>() — no LDS scratch, no DS-ordering reliance.
// C layout: o = mt*16+quad*4+r, column = col.
template<int L>
__device__ __forceinline__ void unit_compute(
    const float (&rg)[CP<L>::KF1 * 8], const _Float16* __restrict__ pk,
    const _Float16* G1, const _Float16* G2, const _Float16* G3,
    const float* __restrict__ w4, float* __restrict__ out, int b0, int ct)
{
  using P = CP<L>;
  const int lane = threadIdx.x & 63;
  const int col  = lane & 15;
  const int quad = lane >> 4;
  const int c = ct * 16 + col;
  const int b = c / P::TWOL1;
  const int m = c - b * P::TWOL1;
  half8 bf[P::KF1];
#pragma unroll
  for (int kf = 0; kf < P::KF1; ++kf)
#pragma unroll
    for (int j = 0; j < 8; ++j) bf[kf][j] = (_Float16)rg[kf * 8 + j];

  // ---- L1 -> packed gated halves ----
  unsigned p1[P::MT][2];
#pragma unroll
  for (int mt = 0; mt < P::MT; ++mt) {
    f32x4 acc = {0.f, 0.f, 0.f, 0.f};
#pragma unroll
    for (int kf = 0; kf < P::KF1; ++kf) {
      const half8 av = *(const half8*)(pk + P::P1 + (size_t)((mt * P::KF1 + kf) * 64 + lane) * 8);
      acc = __builtin_amdgcn_mfma_f32_16x16x32_f16(av, bf[kf], acc, 0, 0, 0);
    }
    const int o0 = mt * 16 + quad * 4;
    const half4 g4 = *(const half4*)(G1 + b * GP + P::GO + o0);
    p1[mt][0] = pack2(acc[0] * (float)g4[0], acc[1] * (float)g4[1]);
    p1[mt][1] = pack2(acc[2] * (float)g4[2], acc[3] * (float)g4[3]);
  }
  half8 bv2[P::KF2];
  exchange<P::MT>(p1, bv2);

  // ---- L2 ----
  unsigned p2[P::MT][2];
#pragma unroll
  for (int mt = 0; mt < P::MT; ++mt) {
    f32x4 acc = {0.f, 0.f, 0.f, 0.f};
#pragma unroll
    for (int kf = 0; kf < P::KF2; ++kf) {
      const half8 av = *(const half8*)(pk + P2BASE + P::P2R + (size_t)((mt * P::KF2 + kf) * 64 + lane) * 8);
      acc = __builtin_amdgcn_mfma_f32_16x16x32_f16(av, bv2[kf], acc, 0, 0, 0);
    }
    const int o0 = mt * 16 + quad * 4;
    const half4 g4 = *(const half4*)(G2 + b * GP + P::GO + o0);
    p2[mt][0] = pack2(acc[0] * (float)g4[0], acc[1] * (float)g4[1]);
    p2[mt][1] = pack2(acc[2] * (float)g4[2], acc[3] * (float)g4[3]);
  }
  half8 bv3[P::KF2];
  exchange<P::MT>(p2, bv3);

  // ---- L3 + folded w4 dot ----
  float s = 0.f;
#pragma unroll
  for (int mt = 0; mt < P::MT; ++mt) {
    f32x4 acc = {0.f, 0.f, 0.f, 0.f};
#pragma unroll
    for (int kf = 0; kf < P::KF2; ++kf) {
      const half8 av = *(const half8*)(pk + P3BASE + P::P2R + (size_t)((mt * P::KF2 + kf) * 64 + lane) * 8);
      acc = __builtin_amdgcn_mfma_f32_16x16x32_f16(av, bv3[kf], acc, 0, 0, 0);
    }
    const int o0 = mt * 16 + quad * 4;
    const half4 g4 = *(const half4*)(G3 + b * GP + P::GO + o0);
#pragma unroll
    for (int r = 0; r < 4; ++r)
      s += acc[r] * (float)g4[r] * w4[P::W4O + o0 + r];
  }
  s += __shfl_xor(s, 16, 64);
  s += __shfl_xor(s, 32, 64);
  if (quad == 0)
    out[(size_t)(b0 + b) * OUT_COLS + L * L + m] = s * P::SCALE;
}

// Chain runner: software pipeline depth 1 on the global B-loads.
template<int L, int CT0, int NCT>
__device__ __forceinline__ void run_chain(
    const float* __restrict__ vraw, const _Float16* __restrict__ pk,
    const _Float16* G1, const _Float16* G2, const _Float16* G3,
    const float* __restrict__ w4, float* __restrict__ out, int b0)
{
  float rg[2][CP<L>::KF1 * 8];
  unit_load<L>(vraw, b0, CT0, rg[0]);
#pragma unroll
  for (int u = 0; u < NCT; ++u) {
    if (u + 1 < NCT) unit_load<L>(vraw, b0, CT0 + u + 1, rg[(u + 1) & 1]);
    unit_compute<L>(rg[u & 1], pk, G1, G2, G3, w4, out, b0, CT0 + u);
  }
}

// Chain runner with pre-issued unit-0 gather (issued before phase 1).
template<int L, int CT0, int NCT>
__device__ __forceinline__ void run_chain_pre(
    const float* __restrict__ vraw, const _Float16* __restrict__ pk,
    const _Float16* G1, const _Float16* G2, const _Float16* G3,
    const float* __restrict__ w4, float* __restrict__ out, int b0,
    const float (&pre)[CP<L>::KF1 * 8])
{
  float rg[2][CP<L>::KF1 * 8];
#pragma unroll
  for (int i = 0; i < CP<L>::KF1 * 8; ++i) rg[0][i] = pre[i];
#pragma unroll
  for (int u = 0; u < NCT; ++u) {
    if (u + 1 < NCT) unit_load<L>(vraw, b0, CT0 + u + 1, rg[(u + 1) & 1]);
    unit_compute<L>(rg[u & 1], pk, G1, G2, G3, w4, out, b0, CT0 + u);
  }
}

// ---------------------------------------------------------------------------
// Scalar (l=0) chain. B-frags: lane col = batch row b (16 valid of 16!).
// Cross-wave tile distribution -> keeps LDS Hs1/Hs2 + barriers.
// ---------------------------------------------------------------------------
__device__ __forceinline__ void load_scal_frags(const float* __restrict__ vraw,
                                                int b0, half8 (&sf)[8])
{
  const int lane = threadIdx.x & 63;
  const int col  = lane & 15;
  const int quad = lane >> 4;
  const float* base = vraw + (size_t)(b0 + col) * IN_DIM + quad * 8;
#pragma unroll
  for (int kf = 0; kf < 8; ++kf) {
    const fvec4 a = *(const fvec4*)(base + kf * 32);
    const fvec4 b2 = *(const fvec4*)(base + kf * 32 + 4);
#pragma unroll
    for (int j = 0; j < 4; ++j) { sf[kf][j] = (_Float16)a[j]; sf[kf][4 + j] = (_Float16)b2[j]; }
  }
}

// W0: scalar L1 (K=256). silu tile = wave; gate tiles = wave*4..+3.
__device__ __forceinline__ void scal_L1(const half8 (&sf)[8],
    const _Float16* __restrict__ pk, _Float16* Hs1, _Float16* G1v)
{
  const int lane = threadIdx.x & 63;
  const int wv   = threadIdx.x >> 6;
  const int col  = lane & 15;
  const int quad = lane >> 4;
  {
    f32x4 acc = {0.f, 0.f, 0.f, 0.f};
#pragma unroll
    for (int kf = 0; kf < 8; ++kf) {
      const half8 av = *(const half8*)(pk + (size_t)((wv * 8 + kf) * 64 + lane) * 8);
      acc = __builtin_amdgcn_mfma_f32_16x16x32_f16(av, sf[kf], acc, 0, 0, 0);
    }
    const int o0 = wv * 16 + quad * 4;
    half4 h;
#pragma unroll
    for (int r = 0; r < 4; ++r) { const float z = acc[r]; h[r] = (_Float16)(z / (1.f + __expf(-z))); }
    *(half4*)(Hs1 + col * HSP + o0) = h;
  }
#pragma unroll
  for (int t = 0; t < 4; ++t) {
    const int mt = wv * 4 + t;
    f32x4 acc = {0.f, 0.f, 0.f, 0.f};
#pragma unroll
    for (int kf = 0; kf < 8; ++kf) {
      const half8 av = *(const half8*)(pk + 16384 + (size_t)((mt * 8 + kf) * 64 + lane) * 8);
      acc = __builtin_amdgcn_mfma_f32_16x16x32_f16(av, sf[kf], acc, 0, 0, 0);
    }
    const int o0 = mt * 16 + quad * 4;
    half4 g;
#pragma unroll
    for (int r = 0; r < 4; ++r) g[r] = (_Float16)(1.f / (1.f + __expf(-acc[r])));
    *(half4*)(G1v + col * GP + o0) = g;
  }
}

// W1: scalar L2 (K=64). Same tile distribution.
__device__ __forceinline__ void scal_mid(const _Float16* HsIn,
    const _Float16* __restrict__ pkS, const _Float16* __restrict__ pkG,
    _Float16* HsOut, _Float16* Gv)
{
  const int lane = threadIdx.x & 63;
  const int wv   = threadIdx.x >> 6;
  const int col  = lane & 15;
  const int quad = lane >> 4;
  half8 bf[2];
#pragma unroll
  for (int kf = 0; kf < 2; ++kf)
    bf[kf] = *(const half8*)(HsIn + col * HSP + kf * 32 + quad * 8);
  {
    f32x4 acc = {0.f, 0.f, 0.f, 0.f};
#pragma unroll
    for (int kf = 0; kf < 2; ++kf) {
      const half8 av = *(const half8*)(pkS + (size_t)((wv * 2 + kf) * 64 + lane) * 8);
      acc = __builtin_amdgcn_mfma_f32_16x16x32_f16(av, bf[kf], acc, 0, 0, 0);
    }
    const int o0 = wv * 16 + quad * 4;
    half4 h;
#pragma unroll
    for (int r = 0; r < 4; ++r) { const float z = acc[r]; h[r] = (_Float16)(z / (1.f + __expf(-z))); }
    *(half4*)(HsOut + col * HSP + o0) = h;
  }
#pragma unroll
  for (int t = 0; t < 4; ++t) {
    const int mt = wv * 4 + t;
    f32x4 acc = {0.f, 0.f, 0.f, 0.f};
#pragma unroll
    for (int kf = 0; kf < 2; ++kf) {
      const half8 av = *(const half8*)(pkG + (size_t)((mt * 2 + kf) * 64 + lane) * 8);
      acc = __builtin_amdgcn_mfma_f32_16x16x32_f16(av, bf[kf], acc, 0, 0, 0);
    }
    const int o0 = mt * 16 + quad * 4;
    half4 g;
#pragma unroll
    for (int r = 0; r < 4; ++r) g[r] = (_Float16)(1.f / (1.f + __expf(-acc[r])));
    *(half4*)(Gv + col * GP + o0) = g;
  }
}

// W2: scalar L3: wave0 does silu tiles + folded w4 dot; waves 1-3 do G3.
__device__ __forceinline__ void scal_last(const _Float16* Hs2,
    const _Float16* __restrict__ pkS, const _Float16* __restrict__ pkG,
    _Float16* G3v, const float* __restrict__ w4, float* __restrict__ out, int b0)
{
  const int lane = threadIdx.x & 63;
  const int wv   = threadIdx.x >> 6;
  const int col  = lane & 15;
  const int quad = lane >> 4;
  half8 bf[2];
#pragma unroll
  for (int kf = 0; kf < 2; ++kf)
    bf[kf] = *(const half8*)(Hs2 + col * HSP + kf * 32 + quad * 8);
  if (wv == 0) {
    float s = 0.f;
#pragma unroll
    for (int mt = 0; mt < 4; ++mt) {
      f32x4 acc = {0.f, 0.f, 0.f, 0.f};
#pragma unroll
      for (int kf = 0; kf < 2; ++kf) {
        const half8 av = *(const half8*)(pkS + (size_t)((mt * 2 + kf) * 64 + lane) * 8);
        acc = __builtin_amdgcn_mfma_f32_16x16x32_f16(av, bf[kf], acc, 0, 0, 0);
      }
      const int o0 = mt * 16 + quad * 4;
#pragma unroll
      for (int r = 0; r < 4; ++r) {
        const float z = acc[r];
        s += (z / (1.f + __expf(-z))) * w4[o0 + r];
      }
    }
    s += __shfl_xor(s, 16, 64);
    s += __shfl_xor(s, 32, 64);
    if (quad == 0) out[(size_t)(b0 + col) * OUT_COLS] = s * 0.125f;
  } else {
    const int t0 = (wv == 1) ? 0 : (wv == 2) ? 6 : 11;
    const int tn = (wv == 1) ? 6 : 5;
    for (int t = 0; t < tn; ++t) {
      const int mt = t0 + t;
      f32x4 acc = {0.f, 0.f, 0.f, 0.f};
#pragma unroll
      for (int kf = 0; kf < 2; ++kf) {
        const half8 av = *(const half8*)(pkG + (size_t)((mt * 2 + kf) * 64 + lane) * 8);
        acc = __builtin_amdgcn_mfma_f32_16x16x32_f16(av, bf[kf], acc, 0, 0, 0);
      }
      const int o0 = mt * 16 + quad * 4;
      half4 g;
#pragma unroll
      for (int r = 0; r < 4; ++r) g[r] = (_Float16)(1.f / (1.f + __expf(-acc[r])));
      *(half4*)(G3v + col * GP + o0) = g;
    }
  }
}

// ---------------------------------------------------------------------------
// Main kernel.
// ---------------------------------------------------------------------------
__global__ __launch_bounds__(256, 2) void fused_decoder(
    const float* __restrict__ vraw, const float* __restrict__ w4,
    const _Float16* __restrict__ pk, float* __restrict__ out)
{
  __shared__ __align__(16) _Float16 smem[SMEM_ELTS];
  _Float16* G1  = smem + OFF_G1;
  _Float16* G2  = smem + OFF_G2;
  _Float16* G3  = smem + OFF_G3;
  _Float16* Hs1 = smem + OFF_HS1;
  _Float16* Hs2 = smem + OFF_HS2;
  const int wv = threadIdx.x >> 6;
  const int b0 = blockIdx.x * B_ROWS;

  half8 sf[8];
  load_scal_frags(vraw, b0, sf);

  // R6: issue each wave's first phase-2 gather now; phase 1 hides its latency.
  float pre[32];
  if (wv == 0)      unit_load<2>(vraw, b0, 0, reinterpret_cast<float(&)[32]>(pre));
  else if (wv == 1) unit_load<1>(vraw, b0, 0, reinterpret_cast<float(&)[32]>(pre));
  else if (wv == 2) unit_load<6>(vraw, b0, 0, reinterpret_cast<float(&)[16]>(pre));
  else              unit_load<5>(vraw, b0, 0, reinterpret_cast<float(&)[16]>(pre));

  scal_L1(sf, pk, Hs1, G1);
  __syncthreads();
  scal_mid(Hs1, pk + P2BASE, pk + P2BASE + 4096, Hs2, G2);
  __syncthreads();
  scal_last(Hs2, pk + P3BASE, pk + P3BASE + 4096, G3, w4, out, b0);
  __syncthreads();

  // phase 2: cost-balanced static wave assignment (no barriers).
  if (wv == 0) {
    run_chain_pre<2, 0, 5>(vraw, pk, G1, G2, G3, w4, out, b0,
                           reinterpret_cast<float(&)[32]>(pre));
    run_chain<3, 0, 4>(vraw, pk, G1, G2, G3, w4, out, b0);
  } else if (wv == 1) {
    run_chain_pre<1, 0, 3>(vraw, pk, G1, G2, G3, w4, out, b0,
                           reinterpret_cast<float(&)[32]>(pre));
    run_chain<3, 4, 3>(vraw, pk, G1, G2, G3, w4, out, b0);
    run_chain<4, 0, 5>(vraw, pk, G1, G2, G3, w4, out, b0);
  } else if (wv == 2) {
    run_chain_pre<6, 0, 13>(vraw, pk, G1, G2, G3, w4, out, b0,
                            reinterpret_cast<float(&)[16]>(pre));
    run_chain<4, 5, 1>(vraw, pk, G1, G2, G3, w4, out, b0);
  } else {
    run_chain_pre<5, 0, 11>(vraw, pk, G1, G2, G3, w4, out, b0,
                            reinterpret_cast<float(&)[16]>(pre));
    run_chain<4, 6, 3>(vraw, pk, G1, G2, G3, w4, out, b0);
  }
}

extern "C" void kernel_launch(void* const* d_in, const int* in_sizes, int n_in,
                              void* d_out, int out_size, void* d_ws, size_t ws_size,
                              hipStream_t stream)
{
  (void)in_sizes; (void)n_in; (void)out_size; (void)ws_size;
  const float* vraw = (const float*)d_in[0];
  const float* w1   = (const float*)d_in[1];
  const float* w2   = (const float*)d_in[2];
  const float* w3   = (const float*)d_in[3];
  const float* w4   = (const float*)d_in[4];
  float* out = (float*)d_out;
  _Float16* packed = (_Float16*)d_ws;   // 172032 elems = 344064 B

  prep_weights<<<84, 256, 0, stream>>>(w1, w2, w3, packed);
  fused_decoder<<<16384 / B_ROWS, 256, 0, stream>>>(vraw, w4, packed, out);
}